// Round 7
// baseline (174.469 us; speedup 1.0000x reference)
//
#include <hip/hip_runtime.h>
#include <hip/hip_bf16.h>

// out[b,o] = sum_i x[b,i]*w[o,i] + bias[o]; M=4096, N=2048, K=2048, fp32 io.
// R7: fuse the fp32->bf16 conversion INTO the GEMM staging (kills the 13us
// cvt dispatch). Model (fits R3/R4/R6 exactly): LDS port ~85 B/cyc/CU on
// reads+writes is the wall at >=16 waves/CU -> gemm floor ~41us. Staging via
// buffer_load f32 -> VALU RNE cvt -> ds_write bf16 keeps LDS bytes identical,
// so gemm stays at its floor while the cvt kernel disappears.
// - 512 thr, 8 waves x 64x32 wave-tiles, 128x128 tile, BK=64, grid 512.
// - __launch_bounds__(512,4): VGPR<=128 so 2 blocks/CU (16 waves) resident.
// - XCD swizzle: each XCD's 64 blocks form an 8x8 tile region (L2 locality
//   for the now-2x f32 staging reads).
// - XOR swizzle (pos p of row r holds chunk p^(r&7)): conflict-free reads
//   AND writes (per-16-lane phase: 2 rows x 32 banks = 2-way = free, m136).

#define M_DIM 4096
#define N_DIM 2048
#define K_DIM 2048
#define BK 64

typedef unsigned short ushort_t;
typedef __attribute__((ext_vector_type(8))) short short8;      // 8 bf16 (A/B frag)
typedef __attribute__((ext_vector_type(4))) float float4v;     // C/D frag

__device__ __forceinline__ unsigned short f2bf_rne(float f) {
    unsigned int u = __builtin_bit_cast(unsigned int, f);
    u += 0x7FFFu + ((u >> 16) & 1u);
    return (unsigned short)(u >> 16);
}

// C = X * W^T + bias.  X:[M,K] f32, W:[N,K] f32, staged as bf16 in LDS.
__global__ void __launch_bounds__(512, 4) gemm_fused(const float* __restrict__ x,
                                                     const float* __restrict__ w,
                                                     const float* __restrict__ bias,
                                                     float* __restrict__ out) {
    __shared__ ushort_t ldsA[128 * BK];   // 16 KB
    __shared__ ushort_t ldsB[128 * BK];   // 16 KB

    const int tid  = threadIdx.x;
    const int wave = tid >> 6;
    const int lane = tid & 63;
    const int quad = lane >> 4;    // 0..3
    const int lrow = lane & 15;    // 0..15

    // XCD-aware swizzle: xcd = blk&7 (round-robin dispatch); 64 blocks/XCD
    // cover an 8x8 tile region -> x-slice + w-slice working set per XCD.
    const int xcd = blockIdx.x & 7;
    const int idx = blockIdx.x >> 3;              // 0..63
    const int bm  = (xcd & 3) * 8 + (idx & 7);    // 0..31
    const int bn  = (xcd >> 2) * 8 + (idx >> 3);  // 0..15
    const int rowBase = bm * 128;
    const int colBase = bn * 128;

    const int waveR = (wave >> 2) * 64;   // 0 or 64
    const int waveC = (wave & 3) * 32;    // 0,32,64,96

    // ---- staging: waves 0-3 stage A rows sgrp*32..+31 (f32->bf16), 4-7 B ----
    // Instr-group j covers 8 rows. Lane L -> row R0+8j+(L>>3), LDS pos L&7,
    // fetching global chunk q = (L&7) ^ ((L>>3)&7)  [pos p holds chunk p^(r&7)].
    const int  sgrp = wave & 3;
    const bool isB  = wave >= 4;
    const int  R0   = sgrp * 32;
    const int  rsub = lane >> 3;     // 0..7
    const int  p    = lane & 7;
    const int  q    = p ^ rsub;
    const float* srcF = isB ? w + (long long)colBase * K_DIM
                            : x + (long long)rowBase * K_DIM;
    const float* gp0 = srcF + (long long)(R0 +  0 + rsub) * K_DIM + q * 8;
    const float* gp1 = srcF + (long long)(R0 +  8 + rsub) * K_DIM + q * 8;
    const float* gp2 = srcF + (long long)(R0 + 16 + rsub) * K_DIM + q * 8;
    const float* gp3 = srcF + (long long)(R0 + 24 + rsub) * K_DIM + q * 8;
    ushort_t* ldsW = isB ? ldsB : ldsA;
    const int wr0 = (R0 +  0 + rsub) * BK + p * 8;
    const int wr1 = (R0 +  8 + rsub) * BK + p * 8;
    const int wr2 = (R0 + 16 + rsub) * BK + p * 8;
    const int wr3 = (R0 + 24 + rsub) * BK + p * 8;

    // ---- fragment read offsets (row r -> r&7 = lrow&7) ----
    const int sw0 = (quad ^ (lrow & 7)) * 8;      // kc=0 chunk; kc=1 at ^32
    const ushort_t* aP = &ldsA[(waveR + lrow) * BK];
    const ushort_t* bP = &ldsB[(waveC + lrow) * BK];

    float4v acc[4][2] = {};

    for (int k0 = 0; k0 < K_DIM; k0 += BK) {
        // load f32 (8x float4), convert, stage bf16 to LDS
        float4v f00 = *(const float4v*)(gp0);
        float4v f01 = *(const float4v*)(gp0 + 4);
        float4v f10 = *(const float4v*)(gp1);
        float4v f11 = *(const float4v*)(gp1 + 4);
        float4v f20 = *(const float4v*)(gp2);
        float4v f21 = *(const float4v*)(gp2 + 4);
        float4v f30 = *(const float4v*)(gp3);
        float4v f31 = *(const float4v*)(gp3 + 4);
        gp0 += BK; gp1 += BK; gp2 += BK; gp3 += BK;

        short8 s0, s1, s2, s3;
#pragma unroll
        for (int e = 0; e < 4; e++) {
            s0[e] = (short)f2bf_rne(f00[e]); s0[4 + e] = (short)f2bf_rne(f01[e]);
            s1[e] = (short)f2bf_rne(f10[e]); s1[4 + e] = (short)f2bf_rne(f11[e]);
            s2[e] = (short)f2bf_rne(f20[e]); s2[4 + e] = (short)f2bf_rne(f21[e]);
            s3[e] = (short)f2bf_rne(f30[e]); s3[4 + e] = (short)f2bf_rne(f31[e]);
        }
        *(short8*)&ldsW[wr0] = s0;
        *(short8*)&ldsW[wr1] = s1;
        *(short8*)&ldsW[wr2] = s2;
        *(short8*)&ldsW[wr3] = s3;
        __syncthreads();

#pragma unroll
        for (int kc = 0; kc < 2; kc++) {
            const int ko = sw0 ^ (kc * 32);
            short8 af[4], bf[2];
#pragma unroll
            for (int mi = 0; mi < 4; mi++)
                af[mi] = *(const short8*)(aP + mi * 16 * BK + ko);
#pragma unroll
            for (int ni = 0; ni < 2; ni++)
                bf[ni] = *(const short8*)(bP + ni * 16 * BK + ko);
#pragma unroll
            for (int mi = 0; mi < 4; mi++)
#pragma unroll
                for (int ni = 0; ni < 2; ni++)
                    acc[mi][ni] = __builtin_amdgcn_mfma_f32_16x16x32_bf16(
                        af[mi], bf[ni], acc[mi][ni], 0, 0, 0);
        }
        __syncthreads();
    }

    // ---- epilogue: C/D layout col=lane&15, row=quad*4+reg ----
#pragma unroll
    for (int ni = 0; ni < 2; ni++) {
        const int col = colBase + waveC + ni * 16 + lrow;
        const float bv = bias[col];
#pragma unroll
        for (int mi = 0; mi < 4; mi++) {
            const int row0 = rowBase + waveR + mi * 16 + quad * 4;
            float4v v = acc[mi][ni];
#pragma unroll
            for (int i = 0; i < 4; i++)
                out[(long long)(row0 + i) * N_DIM + col] = v[i] + bv;
        }
    }
}

extern "C" void kernel_launch(void* const* d_in, const int* in_sizes, int n_in,
                              void* d_out, int out_size, void* d_ws, size_t ws_size,
                              hipStream_t stream) {
    const float* x    = (const float*)d_in[0];   // [4096, 2048]
    const float* w    = (const float*)d_in[1];   // [2048, 2048]
    const float* bias = (const float*)d_in[2];   // [2048]
    float* out = (float*)d_out;                  // [4096, 2048]

    gemm_fused<<<(M_DIM / 128) * (N_DIM / 128), 512, 0, stream>>>(x, w, bias, out);
}

// Round 8
// 133.864 us; speedup vs baseline: 1.3033x; 1.3033x over previous
//
#include <hip/hip_runtime.h>
#include <hip/hip_bf16.h>

// out[b,o] = sum_i x[b,i]*w[o,i] + bias[o]; M=4096, N=2048, K=2048, fp32 io.
// R8: revert R7's fused staging (losing global_load_lds cost 2.5x — ladder
// mistake #1). Attack the LDS-port floor (85 B/cyc/CU, R3/R6 fit exactly):
// move B OFF the LDS port. cvt pre-swizzles W into MFMA fragment-major
// layout (1KB per 16n x 32k fragment, lane-ordered), so GEMM B-frags are
// fully-coalesced global_load_dwordx4 direct to VGPRs (wave-uniform base +
// lane*16). LDS now holds only A: 128 -> 80 KB/block-iter -> floor ~26us.
// B-frag loads issue before the barrier: latency hides in the drain.
// XCD swizzle: per-XCD B slab = 4MB = one L2.
// Structure: 512 thr, 8 waves x 64x32 wave-tiles, 128x128 tile, BK=64,
// grid 512 = 2 blocks/CU (16 waves/CU — R4 showed 8 can't hide latency).

#define M_DIM 4096
#define N_DIM 2048
#define K_DIM 2048
#define BK 64

typedef unsigned short ushort_t;
typedef __attribute__((ext_vector_type(8))) short short8;      // 8 bf16 (A/B frag)
typedef __attribute__((ext_vector_type(4))) float float4v;     // C/D frag
typedef __attribute__((ext_vector_type(8))) unsigned short ushort8;

__device__ __forceinline__ unsigned short f2bf_rne(float f) {
    unsigned int u = __builtin_bit_cast(unsigned int, f);
    u += 0x7FFFu + ((u >> 16) & 1u);
    return (unsigned short)(u >> 16);
}

// One launch: blocks [0, XBLK) convert x row-major; blocks [XBLK, XBLK+WBLK)
// convert w into FRAGMENT-MAJOR layout:
//   wfrag[((nt*64 + kt)*64 + quad*16 + lrow)*8 + e] = bf16(w[nt*16+lrow][kt*32+quad*8+e])
// (nt: n-tile of 16 rows, kt: k-tile of 32, lane index quad*16+lrow).
#define XBLK 4096   // 8.39M x-elems / 8 per thread / 256
#define WBLK 2048   // 4.19M w-elems / 8 per thread / 256

__global__ void __launch_bounds__(256) cvt_both(const float* __restrict__ x,
                                                const float* __restrict__ w,
                                                ushort_t* __restrict__ xb,
                                                ushort_t* __restrict__ wfrag) {
    const int b = blockIdx.x;
    if (b < XBLK) {
        // x: straight vectorized row-major cvt
        const int idx = b * 256 + threadIdx.x;          // ushort8 index
        const float4v* in4 = (const float4v*)x + (size_t)idx * 2;
        float4v a = in4[0];
        float4v c = in4[1];
        ushort8 r;
        r[0] = f2bf_rne(a[0]); r[1] = f2bf_rne(a[1]);
        r[2] = f2bf_rne(a[2]); r[3] = f2bf_rne(a[3]);
        r[4] = f2bf_rne(c[0]); r[5] = f2bf_rne(c[1]);
        r[6] = f2bf_rne(c[2]); r[7] = f2bf_rne(c[3]);
        ((ushort8*)xb)[idx] = r;
    } else {
        // w -> fragment-major. Thread t: lrow=t&15, quad=(t>>4)&3, kt=(t>>6)&63, nt=t>>12.
        const int t    = (b - XBLK) * 256 + threadIdx.x;
        const int lrow = t & 15;
        const int quad = (t >> 4) & 3;
        const int kt   = (t >> 6) & 63;
        const int nt   = t >> 12;
        const float* src = w + (long long)(nt * 16 + lrow) * K_DIM + kt * 32 + quad * 8;
        float4v a = *(const float4v*)(src);
        float4v c = *(const float4v*)(src + 4);
        ushort8 r;
        r[0] = f2bf_rne(a[0]); r[1] = f2bf_rne(a[1]);
        r[2] = f2bf_rne(a[2]); r[3] = f2bf_rne(a[3]);
        r[4] = f2bf_rne(c[0]); r[5] = f2bf_rne(c[1]);
        r[6] = f2bf_rne(c[2]); r[7] = f2bf_rne(c[3]);
        // write offset: ((nt*64+kt)*64 + (t&63)) * 8  — fully coalesced
        ((ushort8*)wfrag)[(size_t)((nt * 64 + kt) * 64) + (t & 63)] = r;
    }
}

// ---------------- async global -> LDS (16B per lane; dest = base + lane*16) ----
__device__ __forceinline__ void async_load16(const void* g, void* l) {
    __builtin_amdgcn_global_load_lds(
        (const __attribute__((address_space(1))) void*)(g),
        (__attribute__((address_space(3))) void*)(l), 16, 0, 0);
}

// ---------------- bf16 MFMA GEMM, C = Xb * Wfrag^T + bias ----------------
// Xb: [M,K] bf16 row-major (LDS-staged, XOR swizzle); W: fragment-major (direct).
// Block: 128x128 tile, 512 threads = 8 waves in 2(row) x 4(col); wave-tile 64x32.
__global__ void __launch_bounds__(512, 4) gemm_bf16(const ushort_t* __restrict__ xb,
                                                    const ushort_t* __restrict__ wfrag,
                                                    const float* __restrict__ bias,
                                                    float* __restrict__ out) {
    __shared__ ushort_t ldsA[128 * BK];   // 16 KB (A only)

    const int tid  = threadIdx.x;
    const int wave = tid >> 6;
    const int lane = tid & 63;
    const int quad = lane >> 4;    // 0..3
    const int lrow = lane & 15;    // 0..15

    // XCD swizzle: xcd = blk&7 (round-robin dispatch); 64 blocks/XCD form an
    // 8(bm) x 8(bn) region -> per-XCD B slab 8*128 cols * 2048 k * 2B = 4MB = L2.
    const int xcd = blockIdx.x & 7;
    const int idx = blockIdx.x >> 3;              // 0..63
    const int bm  = (xcd & 3) * 8 + (idx & 7);    // 0..31
    const int bn  = (xcd >> 2) * 8 + (idx >> 3);  // 0..15
    const int rowBase = bm * 128;
    const int colBase = bn * 128;

    const int waveR = (wave >> 2) * 64;   // 0 or 64
    const int waveC = (wave & 3) * 32;    // 0,32,64,96

    // ---- A staging: each wave stages rows wave*16..+15 (2 instrs x 8 rows) ----
    // Rows are 128B = 8 chunks of 16B. Lane L -> row +(L>>3), pos L&7; XOR
    // swizzle (pos p of row r holds chunk p^(r&7)): fetch chunk q=(L&7)^(L>>3).
    const int R0 = wave * 16;
    const int q  = (lane & 7) ^ (lane >> 3);
    const ushort_t* gA0 = xb + (long long)(rowBase + R0 + (lane >> 3)) * K_DIM + q * 8;
    const ushort_t* gA1 = gA0 + (long long)8 * K_DIM;
    ushort_t* lA0 = ldsA + R0 * BK;        // wave-uniform
    ushort_t* lA1 = ldsA + (R0 + 8) * BK;

    // ---- B fragment pointer (fragment-major, coalesced lane*16B) ----
    // nt0 = first n-tile of this wave's column strip; frag (nt,kt) at
    // (nt*64+kt)*512 ushorts. Per iter kt advances by 2 (BK=64 = 2 k-tiles).
    const int nt0 = (colBase + waveC) >> 4;
    const ushort_t* bPtr = wfrag + (long long)nt0 * 64 * 512 + (long long)lane * 8;

    // ---- A fragment read offsets (row r -> r&7 = lrow&7) ----
    const int sw0 = (quad ^ (lrow & 7)) * 8;      // kc=0 chunk; kc=1 at ^32
    const ushort_t* aP = &ldsA[(waveR + lrow) * BK];

    float4v acc[4][2] = {};

    for (int k0 = 0; k0 < K_DIM; k0 += BK) {
        async_load16(gA0, lA0);
        async_load16(gA1, lA1);
        gA0 += BK; gA1 += BK;

        // B-frags for this iter: issue BEFORE the barrier so the L2 latency
        // hides inside the vmcnt(0) drain we already pay.
        short8 bf00 = *(const short8*)(bPtr);                   // ni=0, kc=0
        short8 bf01 = *(const short8*)(bPtr + 512);             // ni=0, kc=1
        short8 bf10 = *(const short8*)(bPtr + 64 * 512);        // ni=1, kc=0
        short8 bf11 = *(const short8*)(bPtr + 64 * 512 + 512);  // ni=1, kc=1
        bPtr += 2 * 512;

        __syncthreads();

        short8 af0[4], af1[4];
#pragma unroll
        for (int mi = 0; mi < 4; mi++) {
            af0[mi] = *(const short8*)(aP + mi * 16 * BK + sw0);
            af1[mi] = *(const short8*)(aP + mi * 16 * BK + (sw0 ^ 32));
        }
#pragma unroll
        for (int mi = 0; mi < 4; mi++) {
            acc[mi][0] = __builtin_amdgcn_mfma_f32_16x16x32_bf16(af0[mi], bf00, acc[mi][0], 0, 0, 0);
            acc[mi][1] = __builtin_amdgcn_mfma_f32_16x16x32_bf16(af0[mi], bf10, acc[mi][1], 0, 0, 0);
        }
#pragma unroll
        for (int mi = 0; mi < 4; mi++) {
            acc[mi][0] = __builtin_amdgcn_mfma_f32_16x16x32_bf16(af1[mi], bf01, acc[mi][0], 0, 0, 0);
            acc[mi][1] = __builtin_amdgcn_mfma_f32_16x16x32_bf16(af1[mi], bf11, acc[mi][1], 0, 0, 0);
        }
        __syncthreads();
    }

    // ---- epilogue: C/D layout col=lane&15, row=quad*4+reg ----
#pragma unroll
    for (int ni = 0; ni < 2; ni++) {
        const int col = colBase + waveC + ni * 16 + lrow;
        const float bv = bias[col];
#pragma unroll
        for (int mi = 0; mi < 4; mi++) {
            const int row0 = rowBase + waveR + mi * 16 + quad * 4;
            float4v v = acc[mi][ni];
#pragma unroll
            for (int i = 0; i < 4; i++)
                out[(long long)(row0 + i) * N_DIM + col] = v[i] + bv;
        }
    }
}

// ---------------- fallback (ws too small): fp32 naive ----------------
__global__ void __launch_bounds__(256) linear_naive(const float* __restrict__ x,
                                                    const float* __restrict__ w,
                                                    const float* __restrict__ bias,
                                                    float* __restrict__ out) {
    __shared__ float xs[K_DIM];
    const int b = blockIdx.y;
    const int o = blockIdx.x * 256 + threadIdx.x;
    for (int k = threadIdx.x; k < K_DIM; k += 256)
        xs[k] = x[(long long)b * K_DIM + k];
    __syncthreads();
    const float4v* wr = (const float4v*)(w + (long long)o * K_DIM);
    float s = 0.f;
    for (int k4 = 0; k4 < K_DIM / 4; k4++) {
        float4v wv = wr[k4];
        float4v xv = *(const float4v*)&xs[k4 * 4];
        s += xv[0] * wv[0] + xv[1] * wv[1] + xv[2] * wv[2] + xv[3] * wv[3];
    }
    out[(long long)b * N_DIM + o] = s + bias[o];
}

extern "C" void kernel_launch(void* const* d_in, const int* in_sizes, int n_in,
                              void* d_out, int out_size, void* d_ws, size_t ws_size,
                              hipStream_t stream) {
    const float* x    = (const float*)d_in[0];   // [4096, 2048]
    const float* w    = (const float*)d_in[1];   // [2048, 2048]
    const float* bias = (const float*)d_in[2];   // [2048]
    float* out = (float*)d_out;                  // [4096, 2048]

    const size_t xElems = (size_t)M_DIM * K_DIM;   // 8388608
    const size_t wElems = (size_t)N_DIM * K_DIM;   // 4194304
    const size_t need = (xElems + wElems) * sizeof(ushort_t);  // ~25.2 MB

    if (ws_size >= need) {
        ushort_t* xb    = (ushort_t*)d_ws;
        ushort_t* wfrag = xb + xElems;
        cvt_both<<<XBLK + WBLK, 256, 0, stream>>>(x, w, xb, wfrag);
        gemm_bf16<<<(M_DIM / 128) * (N_DIM / 128), 512, 0, stream>>>(xb, wfrag, bias, out);
    } else {
        dim3 grid(N_DIM / 256, M_DIM);
        linear_naive<<<grid, 256, 0, stream>>>(x, w, bias, out);
    }
}